// Round 4
// baseline (77.522 us; speedup 1.0000x reference)
//
#include <hip/hip_runtime.h>

#define N 512
#define ADJW (N/64)
typedef unsigned long long ull;

#define ADJ_OFF   0
#define CNT_OFF   32768
#define PAIRS_OFF 32832

__device__ __forceinline__ float limit_period_f(float v){
    const float TWO_PI_F = 6.2831853071795864769f;
    return v - floorf(v/TWO_PI_F + 0.5f)*TWO_PI_F;
}

// Kernel A: cheap conservative test on all pairs, zero adj rows, append
// surviving (i,j) to global pair list (block-compacted, 1 atomic per block).
__global__ __launch_bounds__(512) void pair_kernel(const float* __restrict__ boxes,
                                                   ull* __restrict__ adj,
                                                   int* __restrict__ cnt,
                                                   unsigned* __restrict__ pairs,
                                                   int cap){
    int i = blockIdx.x;
    int t = threadIdx.x;
    int lane = t & 63, w = t >> 6;
    __shared__ int s_wcnt[8];
    __shared__ int s_base;
    if(t < ADJW) adj[i*ADJW + t] = 0ull;

    float bi0=boxes[i*7+0], bi1=boxes[i*7+1], bi2=boxes[i*7+2], bi3=boxes[i*7+3],
          bi4=boxes[i*7+4], bi5=boxes[i*7+5];
    int j = t;
    float bj0=boxes[j*7+0], bj1=boxes[j*7+1], bj2=boxes[j*7+2], bj3=boxes[j*7+3],
          bj4=boxes[j*7+4], bj5=boxes[j*7+5];
    float topi = bi2 + bi3*0.5f, boti = bi2 - bi3*0.5f;
    float topj = bj2 + bj3*0.5f, botj = bj2 - bj3*0.5f;
    float oh = fminf(topi, topj) - fmaxf(boti, botj);
    float dx = bi0 - bj0, dy = bi1 - bj1;
    float ra = 0.5f*sqrtf(bi5*bi5 + bi4*bi4);
    float rb = 0.5f*sqrtf(bj5*bj5 + bj4*bj4);
    float rr = ra + rb + 0.01f;
    bool cand = (dx*dx + dy*dy <= rr*rr) && (oh > 0.0f);

    ull m = __ballot(cand);
    if(lane == 0) s_wcnt[w] = __popcll(m);
    int prefix = __popcll(m & ((1ull<<lane) - 1ull));
    __syncthreads();
    int base = 0, C = 0;
    #pragma unroll
    for(int k=0;k<8;++k){ int c = s_wcnt[k]; if(k < w) base += c; C += c; }
    if(t == 0) s_base = atomicAdd(cnt, C);
    __syncthreads();
    if(cand){
        int pos = s_base + base + prefix;
        if(pos < cap) pairs[pos] = ((unsigned)i << 16) | (unsigned)j;
    }
}

// Kernel B: full polygon-clip geometry, one pair per thread (packed waves).
__global__ __launch_bounds__(512) void geom_kernel(const float* __restrict__ boxes,
                                                   const unsigned* __restrict__ pairs,
                                                   const int* __restrict__ cnt,
                                                   ull* __restrict__ adj,
                                                   int cap){
    int n = *cnt; if(n > cap) n = cap;
    for(int idx = blockIdx.x*blockDim.x + threadIdx.x; idx < n; idx += gridDim.x*blockDim.x){
        unsigned p = pairs[idx];
        int i = (int)(p >> 16);
        int j = (int)(p & 0xFFFFu);
        float bi0=boxes[i*7+0], bi1=boxes[i*7+1], bi2=boxes[i*7+2], bi3=boxes[i*7+3],
              bi4=boxes[i*7+4], bi5=boxes[i*7+5], bi6=boxes[i*7+6];
        float cj0=boxes[j*7+0], cj1=boxes[j*7+1], cj2=boxes[j*7+2], cj3=boxes[j*7+3],
              cj4=boxes[j*7+4], cj5=boxes[j*7+5], cj6=boxes[j*7+6];
        float voli = bi3*bi4*bi5;
        float volj = cj3*cj4*cj5;
        float topi = bi2 + bi3*0.5f, boti = bi2 - bi3*0.5f;
        float topj = cj2 + cj3*0.5f, botj = cj2 - cj3*0.5f;
        float oh = fminf(topi, topj) - fmaxf(boti, botj);   // > 0 for candidates

        const float tx[4] = {0.5f, 0.5f, -0.5f, -0.5f};
        const float ty[4] = {0.5f, -0.5f, -0.5f, 0.5f};
        float yawi = limit_period_f(bi6);
        float yawj = limit_period_f(cj6);
        float cA = cosf(yawi), sA = sinf(yawi);
        float cB = cosf(yawj), sB = sinf(yawj);
        float axv[4], ayv[4], bxv[4], byv[4];
        #pragma unroll
        for(int k=0;k<4;++k){
            float px = tx[k]*bi5, py = ty[k]*bi4;
            axv[k] = px*cA - py*sA + bi0;
            ayv[k] = px*sA + py*cA + bi1;
            float qx = tx[k]*cj5, qy = ty[k]*cj4;
            bxv[k] = qx*cB - qy*sB + cj0;
            byv[k] = qx*sB + qy*cB + cj1;
        }
        float cx[24], cy[24], ang[24];
        unsigned vm = 0u;
        const float EPSQ = 1e-5f;
        #pragma unroll
        for(int e1=0;e1<4;++e1){
            float a1x=axv[e1], a1y=ayv[e1];
            float d1x=axv[(e1+1)&3]-a1x, d1y=ayv[(e1+1)&3]-a1y;
            #pragma unroll
            for(int e2=0;e2<4;++e2){
                float b1x=bxv[e2], b1y=byv[e2];
                float d2x=bxv[(e2+1)&3]-b1x, d2y=byv[(e2+1)&3]-b1y;
                float den = d1x*d2y - d1y*d2x;
                bool okd = fabsf(den) > 1e-8f;
                float dens = okd ? den : 1e-8f;
                float wx = b1x-a1x, wy = b1y-a1y;
                float tt = (wx*d2y - wy*d2x)/dens;
                float uu = (wx*d1y - wy*d1x)/dens;
                bool ok = okd && (tt>=0.f) && (tt<=1.f) && (uu>=0.f) && (uu<=1.f);
                int k = e1*4+e2;
                cx[k] = a1x + tt*d1x;
                cy[k] = a1y + tt*d1y;
                if(ok) vm |= (1u<<k);
            }
        }
        #pragma unroll
        for(int k=0;k<4;++k){
            float px=axv[k], py=ayv[k];
            bool le=true, ge=true;
            #pragma unroll
            for(int e=0;e<4;++e){
                float qx=bxv[e], qy=byv[e];
                float ux=bxv[(e+1)&3]-qx, uy=byv[(e+1)&3]-qy;
                float cc = ux*(py-qy) - uy*(px-qx);
                le = le && (cc <= EPSQ);
                ge = ge && (cc >= -EPSQ);
            }
            cx[16+k]=px; cy[16+k]=py;
            if(le||ge) vm |= (1u<<(16+k));
        }
        #pragma unroll
        for(int k=0;k<4;++k){
            float px=bxv[k], py=byv[k];
            bool le=true, ge=true;
            #pragma unroll
            for(int e=0;e<4;++e){
                float qx=axv[e], qy=ayv[e];
                float ux=axv[(e+1)&3]-qx, uy=ayv[(e+1)&3]-qy;
                float cc = ux*(py-qy) - uy*(px-qx);
                le = le && (cc <= EPSQ);
                ge = ge && (cc >= -EPSQ);
            }
            cx[20+k]=px; cy[20+k]=py;
            if(le||ge) vm |= (1u<<(20+k));
        }
        float cntf = 0.f, sx=0.f, sy=0.f;
        #pragma unroll
        for(int k=0;k<24;++k){
            if((vm>>k)&1u){ cntf += 1.f; sx += cx[k]; sy += cy[k]; }
        }
        float denomc = fmaxf(cntf, 1.f);
        float cenx = sx/denomc, ceny = sy/denomc;
        #pragma unroll
        for(int k=0;k<24;++k){
            ang[k] = ((vm>>k)&1u) ? atan2f(cy[k]-ceny, cx[k]-cenx) : 1e9f;
        }
        int cN = __popc(vm);
        unsigned used = ~vm;
        float fx=0.f, fy=0.f, pxp=0.f, pyp=0.f, acc=0.f;
        for(int k=0;k<cN;++k){
            float best = 1e30f; float bx2=0.f, by2=0.f; int bsel=0;
            #pragma unroll
            for(int t2=0;t2<24;++t2){
                bool better = (((used>>t2)&1u)==0u) && (ang[t2] < best);
                if(better){ best=ang[t2]; bx2=cx[t2]-cenx; by2=cy[t2]-ceny; bsel=t2; }
            }
            used |= (1u<<bsel);
            if(k==0){ fx=bx2; fy=by2; }
            else { acc += pxp*by2 - pyp*bx2; }
            pxp=bx2; pyp=by2;
        }
        acc += pxp*fy - pyp*fx;
        float area = 0.5f*fabsf(acc);
        float inter_bev = (cntf >= 3.f) ? area : 0.f;
        float inter = inter_bev * oh;
        float iou = inter / fmaxf(voli+volj-inter, 1e-6f);
        if(iou > 0.1f){
            unsigned* adj32 = (unsigned*)adj;
            atomicOr(&adj32[i*(ADJW*2) + (j>>5)], 1u << (j&31));
        }
    }
}

// single block: clustering (wave 0, pipelined seed-scan) + CSR fusion + outputs
__global__ __launch_bounds__(512) void cluster_fuse_kernel(
        const float* __restrict__ boxes,
        const float* __restrict__ scores,
        const ull* __restrict__ adj,
        const int* __restrict__ fhp,
        const int* __restrict__ fwp,
        float* __restrict__ out){
    const float PI_F      = 3.14159265358979323846f;
    const float HALF_PI_F = 1.57079632679489662f;
    const float TWO_PI_F  = 6.2831853071795864769f;
    int t = threadIdx.x;
    int lane = t & 63, w = t >> 6;

    __shared__ ull   s_adj[N*ADJW];   // 32 KB
    __shared__ float s_sc[N], s_dir[N];
    __shared__ int   s_ci[N];
    __shared__ int   s_cnt[N], s_off[N], s_pos[N], s_mem[N];
    __shared__ float s_dref[N], s_ssum[N], s_smax[N];
    __shared__ float s_val[8][N];
    __shared__ unsigned char s_keep[N];
    __shared__ int   s_wsum[8];

    float b0=boxes[t*7+0], b1=boxes[t*7+1], b2=boxes[t*7+2], b3=boxes[t*7+3],
          b4=boxes[t*7+4], b5=boxes[t*7+5], b6=boxes[t*7+6];
    float dir = limit_period_f(b6);
    float sc  = scores[t];
    s_sc[t] = sc;
    s_dir[t] = dir;
    s_cnt[t] = 0;
    #pragma unroll
    for(int k=0;k<ADJW;++k) s_adj[k*N + t] = adj[k*N + t];
    __syncthreads();

    // ---- clustering: wave 0, ascending seed scan with 8-deep byte prefetch ----
    // Seeds (first-unassigned indices) are strictly increasing, so visiting
    // rows 0..511 in order with "is r unassigned?" as the seed test is exactly
    // equivalent to the reference's argmax(ci==0) loop.
    if(t < 64){
        int mc[8] = {0,0,0,0,0,0,0,0};
        unsigned myset = 0u;
        int cid = 1;
        const unsigned char* ab = (const unsigned char*)s_adj;
        unsigned buf[8];
        #pragma unroll
        for(int k=0;k<8;++k) buf[k] = (unsigned)ab[k*64 + t];
        for(int c=0;c<64;++c){
            unsigned cur[8];
            #pragma unroll
            for(int k=0;k<8;++k) cur[k] = buf[k];
            if(c < 63){
                #pragma unroll
                for(int k=0;k<8;++k) buf[k] = (unsigned)ab[(c*8 + 8 + k)*64 + t];
            }
            bool owner = (t == c);
            #pragma unroll
            for(int k=0;k<8;++k){
                bool mine = owner && (((myset >> k) & 1u) == 0u);
                if(__ballot(mine)){
                    unsigned byte = cur[k];
                    #pragma unroll
                    for(int q=0;q<8;++q){ if((byte>>q)&1u) mc[q] = cid; }
                    myset |= byte;
                    cid++;
                }
            }
        }
        #pragma unroll
        for(int k=0;k<8;++k) s_ci[t*8+k] = mc[k];
    }
    __syncthreads();

    // ---- per-segment counts via LDS atomics ----
    int myci = s_ci[t];
    atomicAdd(&s_cnt[myci-1], 1);
    __syncthreads();
    int icnt = s_cnt[t];            // thread t owns segment t+1

    // ---- exclusive prefix sum: shfl wave-scan + cross-wave fixup ----
    int v = icnt;
    #pragma unroll
    for(int d=1; d<64; d<<=1){
        int u = __shfl_up(v, d);
        if(lane >= d) v += u;
    }
    if(lane == 63) s_wsum[w] = v;
    __syncthreads();
    int woff = 0;
    #pragma unroll
    for(int k=0;k<8;++k){ if(k < w) woff += s_wsum[k]; }
    int excl = woff + v - icnt;
    s_off[t] = excl;
    s_pos[t] = excl;
    __syncthreads();

    // ---- scatter members (unordered), then owner sorts ascending ----
    int r = atomicAdd(&s_pos[myci-1], 1);
    s_mem[r] = t;
    __syncthreads();
    int base = s_off[t];
    for(int a=1;a<icnt;++a){
        int key = s_mem[base+a];
        int b = a-1;
        while(b >= 0 && s_mem[base+b] > key){ s_mem[base+b+1] = s_mem[base+b]; --b; }
        s_mem[base+b+1] = key;
    }

    // ---- owner reductions in exact ascending order ----
    float smax = -1e30f, ssum = 0.f;
    for(int k=0;k<icnt;++k){
        int i = s_mem[base+k];
        smax = fmaxf(smax, s_sc[i]);
        ssum += s_sc[i];
    }
    float dref = -1e9f;
    for(int k=0;k<icnt;++k){
        int i = s_mem[base+k];
        float vv = (s_sc[i] == smax) ? s_dir[i] : -1e9f;
        dref = fmaxf(dref, vv);
    }
    float slt = 0.f, sle = 0.f;
    for(int k=0;k<icnt;++k){
        int i = s_mem[base+k];
        float diff = fabsf(s_dir[i] - dref);
        diff = (diff > PI_F) ? (TWO_PI_F - diff) : diff;
        if(diff > HALF_PI_F) slt += s_sc[i]; else sle += s_sc[i];
    }
    s_smax[t] = smax;
    s_ssum[t] = ssum;
    s_dref[t] = dref;
    s_keep[t] = (slt <= sle) ? 1 : 0;
    __syncthreads();

    // ---- per-box: flip, dir2, sn, weighted values (trig once per box) ----
    {
        int ow = myci - 1;
        float drefb = s_dref[ow];
        float diff = fabsf(dir - drefb);
        diff = (diff > PI_F) ? (TWO_PI_F - diff) : diff;
        bool gt = diff > HALF_PI_F;
        bool keep = s_keep[ow] != 0;
        bool flip = keep ? gt : !gt;
        float d2 = limit_period_f(dir + (flip ? PI_F : 0.f));
        float sn = sc / s_ssum[ow];
        s_val[0][t] = sinf(d2)*sn;
        s_val[1][t] = cosf(d2)*sn;
        s_val[2][t] = b0*sn;
        s_val[3][t] = b1*sn;
        s_val[4][t] = b2*sn;
        s_val[5][t] = b3*sn;
        s_val[6][t] = b4*sn;
        s_val[7][t] = b5*sn;
    }
    __syncthreads();

    // ---- owner weighted sums (ascending member order) ----
    float ssin=0.f, scos=0.f;
    float cd[6] = {0.f,0.f,0.f,0.f,0.f,0.f};
    for(int k=0;k<icnt;++k){
        int i = s_mem[base+k];
        ssin  += s_val[0][i];
        scos  += s_val[1][i];
        cd[0] += s_val[2][i];
        cd[1] += s_val[3][i];
        cd[2] += s_val[4][i];
        cd[3] += s_val[5][i];
        cd[4] += s_val[6][i];
        cd[5] += s_val[7][i];
    }
    float theta = atan2f(ssin, scos);

    // ---- epilogue ----
    bool valid = icnt > 0;
    float bf[7];
    #pragma unroll
    for(int d=0;d<6;++d) bf[d] = valid ? cd[d] : 0.f;
    bf[6] = valid ? theta : 0.f;
    {
        float cth=cosf(bf[6]), sth=sinf(bf[6]);
        const float tx[4]={0.5f,0.5f,-0.5f,-0.5f};
        const float ty[4]={0.5f,-0.5f,-0.5f,0.5f};
        bool inb = true;
        #pragma unroll
        for(int k=0;k<4;++k){
            float pxl = tx[k]*bf[5], pyl = ty[k]*bf[4];
            float gx = pxl*cth - pyl*sth + bf[0];
            float gy = pxl*sth + pyl*cth + bf[1];
            inb = inb && (gx > -140.8f) && (gx < 140.8f) && (gy > -40.0f) && (gy < 40.0f);
        }
        valid = valid && inb;
    }
    if(!valid){
        #pragma unroll
        for(int d=0;d<7;++d) bf[d]=0.f;
    }
    float sf = valid ? s_smax[t] : 0.f;
    int fh = *fhp, fw = *fwp;
    float ghf = (float)((40.0 - (-40.0)) / (double)fh);
    float gwf = (float)((140.8 - (-140.8)) / (double)fw);
    float gcx = (bf[0] + 140.8f) / gwf;
    float gcy = (bf[1] + 40.0f) / ghf;
    float gox = bf[5]*0.5f / gwf;
    float goy = bf[4]*0.5f / ghf + 1.0f;
    float xmin = fmaxf(gcx - gox, 0.f);
    float xmax = fminf(gcx + gox, (float)fw - 1.0f);
    float ymin = fmaxf(gcy - goy, 0.f);
    float ymax = fminf(gcy + goy, (float)fh - 1.0f);
    int r0 = (int)xmin, r1 = (int)xmax, r2 = (int)ymin, r3 = (int)ymax;
    if(!valid){ r0=0; r1=0; r2=0; r3=0; }
    #pragma unroll
    for(int d=0;d<7;++d) out[t*7+d] = bf[d];
    out[N*7 + t] = sf;
    out[N*8 + t] = valid ? 1.f : 0.f;
    out[N*9 + t*4 + 0] = (float)r0;
    out[N*9 + t*4 + 1] = (float)r1;
    out[N*9 + t*4 + 2] = (float)r2;
    out[N*9 + t*4 + 3] = (float)r3;
}

extern "C" void kernel_launch(void* const* d_in, const int* in_sizes, int n_in,
                              void* d_out, int out_size, void* d_ws, size_t ws_size,
                              hipStream_t stream) {
    const float* boxes  = (const float*)d_in[0];
    const float* scores = (const float*)d_in[1];
    const int*   fhp    = (const int*)d_in[2];
    const int*   fwp    = (const int*)d_in[3];
    float* out = (float*)d_out;
    char* ws = (char*)d_ws;
    ull*      adj   = (ull*)(ws + ADJ_OFF);        // 32768 B
    int*      cnt   = (int*)(ws + CNT_OFF);        // 64 B
    unsigned* pairs = (unsigned*)(ws + PAIRS_OFF); // rest

    long long avail = (long long)ws_size - (long long)PAIRS_OFF;
    int cap = (int)(avail > 0 ? avail/4 : 0);
    if(cap > N*N) cap = N*N;

    hipMemsetAsync((void*)cnt, 0, 64, stream);
    pair_kernel<<<N, 512, 0, stream>>>(boxes, adj, cnt, pairs, cap);
    geom_kernel<<<16, 512, 0, stream>>>(boxes, pairs, cnt, adj, cap);
    cluster_fuse_kernel<<<1, 512, 0, stream>>>(boxes, scores, adj, fhp, fwp, out);
}

// Round 5
// 72.976 us; speedup vs baseline: 1.0623x; 1.0623x over previous
//
#include <hip/hip_runtime.h>

#define N 512
#define ADJW (N/64)
typedef unsigned long long ull;

#define ADJ_OFF   0
#define CNT_OFF   32768
#define PAIRS_OFF 32832

__device__ __forceinline__ float limit_period_f(float v){
    const float TWO_PI_F = 6.2831853071795864769f;
    return v - floorf(v/TWO_PI_F + 0.5f)*TWO_PI_F;
}

// zero the pair counter (replaces hipMemsetAsync: a rocclr fill dispatch cost ~39us in-graph)
__global__ void init_kernel(int* __restrict__ cnt){
    *cnt = 0;
}

// Kernel A: cheap conservative test on all pairs, zero adj rows, append
// surviving (i,j) to global pair list (block-compacted, 1 atomic per block).
__global__ __launch_bounds__(512) void pair_kernel(const float* __restrict__ boxes,
                                                   ull* __restrict__ adj,
                                                   int* __restrict__ cnt,
                                                   unsigned* __restrict__ pairs,
                                                   int cap){
    int i = blockIdx.x;
    int t = threadIdx.x;
    int lane = t & 63, w = t >> 6;
    __shared__ int s_wcnt[8];
    __shared__ int s_base;
    if(t < ADJW) adj[i*ADJW + t] = 0ull;

    float bi0=boxes[i*7+0], bi1=boxes[i*7+1], bi2=boxes[i*7+2], bi3=boxes[i*7+3],
          bi4=boxes[i*7+4], bi5=boxes[i*7+5];
    int j = t;
    float bj0=boxes[j*7+0], bj1=boxes[j*7+1], bj2=boxes[j*7+2], bj3=boxes[j*7+3],
          bj4=boxes[j*7+4], bj5=boxes[j*7+5];
    float topi = bi2 + bi3*0.5f, boti = bi2 - bi3*0.5f;
    float topj = bj2 + bj3*0.5f, botj = bj2 - bj3*0.5f;
    float oh = fminf(topi, topj) - fmaxf(boti, botj);
    float dx = bi0 - bj0, dy = bi1 - bj1;
    float ra = 0.5f*sqrtf(bi5*bi5 + bi4*bi4);
    float rb = 0.5f*sqrtf(bj5*bj5 + bj4*bj4);
    float rr = ra + rb + 0.01f;
    bool cand = (dx*dx + dy*dy <= rr*rr) && (oh > 0.0f);

    ull m = __ballot(cand);
    if(lane == 0) s_wcnt[w] = __popcll(m);
    int prefix = __popcll(m & ((1ull<<lane) - 1ull));
    __syncthreads();
    int base = 0, C = 0;
    #pragma unroll
    for(int k=0;k<8;++k){ int c = s_wcnt[k]; if(k < w) base += c; C += c; }
    if(t == 0) s_base = atomicAdd(cnt, C);
    __syncthreads();
    if(cand){
        int pos = s_base + base + prefix;
        if(pos < cap) pairs[pos] = ((unsigned)i << 16) | (unsigned)j;
    }
}

// Kernel B: full polygon-clip geometry, one pair per thread (packed waves).
__global__ __launch_bounds__(64) void geom_kernel(const float* __restrict__ boxes,
                                                  const unsigned* __restrict__ pairs,
                                                  const int* __restrict__ cnt,
                                                  ull* __restrict__ adj,
                                                  int cap){
    int n = *cnt; if(n > cap) n = cap;
    for(int idx = blockIdx.x*blockDim.x + threadIdx.x; idx < n; idx += gridDim.x*blockDim.x){
        unsigned p = pairs[idx];
        int i = (int)(p >> 16);
        int j = (int)(p & 0xFFFFu);
        float bi0=boxes[i*7+0], bi1=boxes[i*7+1], bi2=boxes[i*7+2], bi3=boxes[i*7+3],
              bi4=boxes[i*7+4], bi5=boxes[i*7+5], bi6=boxes[i*7+6];
        float cj0=boxes[j*7+0], cj1=boxes[j*7+1], cj2=boxes[j*7+2], cj3=boxes[j*7+3],
              cj4=boxes[j*7+4], cj5=boxes[j*7+5], cj6=boxes[j*7+6];
        float voli = bi3*bi4*bi5;
        float volj = cj3*cj4*cj5;
        float topi = bi2 + bi3*0.5f, boti = bi2 - bi3*0.5f;
        float topj = cj2 + cj3*0.5f, botj = cj2 - cj3*0.5f;
        float oh = fminf(topi, topj) - fmaxf(boti, botj);   // > 0 for candidates

        const float tx[4] = {0.5f, 0.5f, -0.5f, -0.5f};
        const float ty[4] = {0.5f, -0.5f, -0.5f, 0.5f};
        float yawi = limit_period_f(bi6);
        float yawj = limit_period_f(cj6);
        float cA = cosf(yawi), sA = sinf(yawi);
        float cB = cosf(yawj), sB = sinf(yawj);
        float axv[4], ayv[4], bxv[4], byv[4];
        #pragma unroll
        for(int k=0;k<4;++k){
            float px = tx[k]*bi5, py = ty[k]*bi4;
            axv[k] = px*cA - py*sA + bi0;
            ayv[k] = px*sA + py*cA + bi1;
            float qx = tx[k]*cj5, qy = ty[k]*cj4;
            bxv[k] = qx*cB - qy*sB + cj0;
            byv[k] = qx*sB + qy*cB + cj1;
        }
        float cx[24], cy[24], ang[24];
        unsigned vm = 0u;
        const float EPSQ = 1e-5f;
        #pragma unroll
        for(int e1=0;e1<4;++e1){
            float a1x=axv[e1], a1y=ayv[e1];
            float d1x=axv[(e1+1)&3]-a1x, d1y=ayv[(e1+1)&3]-a1y;
            #pragma unroll
            for(int e2=0;e2<4;++e2){
                float b1x=bxv[e2], b1y=byv[e2];
                float d2x=bxv[(e2+1)&3]-b1x, d2y=byv[(e2+1)&3]-b1y;
                float den = d1x*d2y - d1y*d2x;
                bool okd = fabsf(den) > 1e-8f;
                float dens = okd ? den : 1e-8f;
                float wx = b1x-a1x, wy = b1y-a1y;
                float tt = (wx*d2y - wy*d2x)/dens;
                float uu = (wx*d1y - wy*d1x)/dens;
                bool ok = okd && (tt>=0.f) && (tt<=1.f) && (uu>=0.f) && (uu<=1.f);
                int k = e1*4+e2;
                cx[k] = a1x + tt*d1x;
                cy[k] = a1y + tt*d1y;
                if(ok) vm |= (1u<<k);
            }
        }
        #pragma unroll
        for(int k=0;k<4;++k){
            float px=axv[k], py=ayv[k];
            bool le=true, ge=true;
            #pragma unroll
            for(int e=0;e<4;++e){
                float qx=bxv[e], qy=byv[e];
                float ux=bxv[(e+1)&3]-qx, uy=byv[(e+1)&3]-qy;
                float cc = ux*(py-qy) - uy*(px-qx);
                le = le && (cc <= EPSQ);
                ge = ge && (cc >= -EPSQ);
            }
            cx[16+k]=px; cy[16+k]=py;
            if(le||ge) vm |= (1u<<(16+k));
        }
        #pragma unroll
        for(int k=0;k<4;++k){
            float px=bxv[k], py=byv[k];
            bool le=true, ge=true;
            #pragma unroll
            for(int e=0;e<4;++e){
                float qx=axv[e], qy=ayv[e];
                float ux=axv[(e+1)&3]-qx, uy=ayv[(e+1)&3]-qy;
                float cc = ux*(py-qy) - uy*(px-qx);
                le = le && (cc <= EPSQ);
                ge = ge && (cc >= -EPSQ);
            }
            cx[20+k]=px; cy[20+k]=py;
            if(le||ge) vm |= (1u<<(20+k));
        }
        float cntf = 0.f, sx=0.f, sy=0.f;
        #pragma unroll
        for(int k=0;k<24;++k){
            if((vm>>k)&1u){ cntf += 1.f; sx += cx[k]; sy += cy[k]; }
        }
        float denomc = fmaxf(cntf, 1.f);
        float cenx = sx/denomc, ceny = sy/denomc;
        #pragma unroll
        for(int k=0;k<24;++k){
            ang[k] = ((vm>>k)&1u) ? atan2f(cy[k]-ceny, cx[k]-cenx) : 1e9f;
        }
        int cN = __popc(vm);
        unsigned used = ~vm;
        float fx=0.f, fy=0.f, pxp=0.f, pyp=0.f, acc=0.f;
        for(int k=0;k<cN;++k){
            float best = 1e30f; float bx2=0.f, by2=0.f; int bsel=0;
            #pragma unroll
            for(int t2=0;t2<24;++t2){
                bool better = (((used>>t2)&1u)==0u) && (ang[t2] < best);
                if(better){ best=ang[t2]; bx2=cx[t2]-cenx; by2=cy[t2]-ceny; bsel=t2; }
            }
            used |= (1u<<bsel);
            if(k==0){ fx=bx2; fy=by2; }
            else { acc += pxp*by2 - pyp*bx2; }
            pxp=bx2; pyp=by2;
        }
        acc += pxp*fy - pyp*fx;
        float area = 0.5f*fabsf(acc);
        float inter_bev = (cntf >= 3.f) ? area : 0.f;
        float inter = inter_bev * oh;
        float iou = inter / fmaxf(voli+volj-inter, 1e-6f);
        if(iou > 0.1f){
            unsigned* adj32 = (unsigned*)adj;
            atomicOr(&adj32[i*(ADJW*2) + (j>>5)], 1u << (j&31));
        }
    }
}

// single block: clustering (wave 0, pipelined seed-scan) + CSR fusion + outputs
__global__ __launch_bounds__(512) void cluster_fuse_kernel(
        const float* __restrict__ boxes,
        const float* __restrict__ scores,
        const ull* __restrict__ adj,
        const int* __restrict__ fhp,
        const int* __restrict__ fwp,
        float* __restrict__ out){
    const float PI_F      = 3.14159265358979323846f;
    const float HALF_PI_F = 1.57079632679489662f;
    const float TWO_PI_F  = 6.2831853071795864769f;
    int t = threadIdx.x;
    int lane = t & 63, w = t >> 6;

    __shared__ ull   s_adj[N*ADJW];   // 32 KB
    __shared__ float s_sc[N], s_dir[N];
    __shared__ int   s_ci[N];
    __shared__ int   s_cnt[N], s_off[N], s_pos[N], s_mem[N];
    __shared__ float s_dref[N], s_ssum[N], s_smax[N];
    __shared__ float s_val[8][N];
    __shared__ unsigned char s_keep[N];
    __shared__ int   s_wsum[8];

    float b0=boxes[t*7+0], b1=boxes[t*7+1], b2=boxes[t*7+2], b3=boxes[t*7+3],
          b4=boxes[t*7+4], b5=boxes[t*7+5], b6=boxes[t*7+6];
    float dir = limit_period_f(b6);
    float sc  = scores[t];
    s_sc[t] = sc;
    s_dir[t] = dir;
    s_cnt[t] = 0;
    #pragma unroll
    for(int k=0;k<ADJW;++k) s_adj[k*N + t] = adj[k*N + t];
    __syncthreads();

    // ---- clustering: wave 0, ascending seed scan with 8-deep byte prefetch ----
    if(t < 64){
        int mc[8] = {0,0,0,0,0,0,0,0};
        unsigned myset = 0u;
        int cid = 1;
        const unsigned char* ab = (const unsigned char*)s_adj;
        unsigned buf[8];
        #pragma unroll
        for(int k=0;k<8;++k) buf[k] = (unsigned)ab[k*64 + t];
        for(int c=0;c<64;++c){
            unsigned cur[8];
            #pragma unroll
            for(int k=0;k<8;++k) cur[k] = buf[k];
            if(c < 63){
                #pragma unroll
                for(int k=0;k<8;++k) buf[k] = (unsigned)ab[(c*8 + 8 + k)*64 + t];
            }
            bool owner = (t == c);
            #pragma unroll
            for(int k=0;k<8;++k){
                bool mine = owner && (((myset >> k) & 1u) == 0u);
                if(__ballot(mine)){
                    unsigned byte = cur[k];
                    #pragma unroll
                    for(int q=0;q<8;++q){ if((byte>>q)&1u) mc[q] = cid; }
                    myset |= byte;
                    cid++;
                }
            }
        }
        #pragma unroll
        for(int k=0;k<8;++k) s_ci[t*8+k] = mc[k];
    }
    __syncthreads();

    // ---- per-segment counts via LDS atomics ----
    int myci = s_ci[t];
    atomicAdd(&s_cnt[myci-1], 1);
    __syncthreads();
    int icnt = s_cnt[t];            // thread t owns segment t+1

    // ---- exclusive prefix sum: shfl wave-scan + cross-wave fixup ----
    int v = icnt;
    #pragma unroll
    for(int d=1; d<64; d<<=1){
        int u = __shfl_up(v, d);
        if(lane >= d) v += u;
    }
    if(lane == 63) s_wsum[w] = v;
    __syncthreads();
    int woff = 0;
    #pragma unroll
    for(int k=0;k<8;++k){ if(k < w) woff += s_wsum[k]; }
    int excl = woff + v - icnt;
    s_off[t] = excl;
    s_pos[t] = excl;
    __syncthreads();

    // ---- scatter members (unordered), then owner sorts ascending ----
    int r = atomicAdd(&s_pos[myci-1], 1);
    s_mem[r] = t;
    __syncthreads();
    int base = s_off[t];
    for(int a=1;a<icnt;++a){
        int key = s_mem[base+a];
        int b = a-1;
        while(b >= 0 && s_mem[base+b] > key){ s_mem[base+b+1] = s_mem[base+b]; --b; }
        s_mem[base+b+1] = key;
    }

    // ---- owner reductions in exact ascending order ----
    float smax = -1e30f, ssum = 0.f;
    for(int k=0;k<icnt;++k){
        int i = s_mem[base+k];
        smax = fmaxf(smax, s_sc[i]);
        ssum += s_sc[i];
    }
    float dref = -1e9f;
    for(int k=0;k<icnt;++k){
        int i = s_mem[base+k];
        float vv = (s_sc[i] == smax) ? s_dir[i] : -1e9f;
        dref = fmaxf(dref, vv);
    }
    float slt = 0.f, sle = 0.f;
    for(int k=0;k<icnt;++k){
        int i = s_mem[base+k];
        float diff = fabsf(s_dir[i] - dref);
        diff = (diff > PI_F) ? (TWO_PI_F - diff) : diff;
        if(diff > HALF_PI_F) slt += s_sc[i]; else sle += s_sc[i];
    }
    s_smax[t] = smax;
    s_ssum[t] = ssum;
    s_dref[t] = dref;
    s_keep[t] = (slt <= sle) ? 1 : 0;
    __syncthreads();

    // ---- per-box: flip, dir2, sn, weighted values (trig once per box) ----
    {
        int ow = myci - 1;
        float drefb = s_dref[ow];
        float diff = fabsf(dir - drefb);
        diff = (diff > PI_F) ? (TWO_PI_F - diff) : diff;
        bool gt = diff > HALF_PI_F;
        bool keep = s_keep[ow] != 0;
        bool flip = keep ? gt : !gt;
        float d2 = limit_period_f(dir + (flip ? PI_F : 0.f));
        float sn = sc / s_ssum[ow];
        s_val[0][t] = sinf(d2)*sn;
        s_val[1][t] = cosf(d2)*sn;
        s_val[2][t] = b0*sn;
        s_val[3][t] = b1*sn;
        s_val[4][t] = b2*sn;
        s_val[5][t] = b3*sn;
        s_val[6][t] = b4*sn;
        s_val[7][t] = b5*sn;
    }
    __syncthreads();

    // ---- owner weighted sums (ascending member order) ----
    float ssin=0.f, scos=0.f;
    float cd[6] = {0.f,0.f,0.f,0.f,0.f,0.f};
    for(int k=0;k<icnt;++k){
        int i = s_mem[base+k];
        ssin  += s_val[0][i];
        scos  += s_val[1][i];
        cd[0] += s_val[2][i];
        cd[1] += s_val[3][i];
        cd[2] += s_val[4][i];
        cd[3] += s_val[5][i];
        cd[4] += s_val[6][i];
        cd[5] += s_val[7][i];
    }
    float theta = atan2f(ssin, scos);

    // ---- epilogue ----
    bool valid = icnt > 0;
    float bf[7];
    #pragma unroll
    for(int d=0;d<6;++d) bf[d] = valid ? cd[d] : 0.f;
    bf[6] = valid ? theta : 0.f;
    {
        float cth=cosf(bf[6]), sth=sinf(bf[6]);
        const float tx[4]={0.5f,0.5f,-0.5f,-0.5f};
        const float ty[4]={0.5f,-0.5f,-0.5f,0.5f};
        bool inb = true;
        #pragma unroll
        for(int k=0;k<4;++k){
            float pxl = tx[k]*bf[5], pyl = ty[k]*bf[4];
            float gx = pxl*cth - pyl*sth + bf[0];
            float gy = pxl*sth + pyl*cth + bf[1];
            inb = inb && (gx > -140.8f) && (gx < 140.8f) && (gy > -40.0f) && (gy < 40.0f);
        }
        valid = valid && inb;
    }
    if(!valid){
        #pragma unroll
        for(int d=0;d<7;++d) bf[d]=0.f;
    }
    float sf = valid ? s_smax[t] : 0.f;
    int fh = *fhp, fw = *fwp;
    float ghf = (float)((40.0 - (-40.0)) / (double)fh);
    float gwf = (float)((140.8 - (-140.8)) / (double)fw);
    float gcx = (bf[0] + 140.8f) / gwf;
    float gcy = (bf[1] + 40.0f) / ghf;
    float gox = bf[5]*0.5f / gwf;
    float goy = bf[4]*0.5f / ghf + 1.0f;
    float xmin = fmaxf(gcx - gox, 0.f);
    float xmax = fminf(gcx + gox, (float)fw - 1.0f);
    float ymin = fmaxf(gcy - goy, 0.f);
    float ymax = fminf(gcy + goy, (float)fh - 1.0f);
    int r0 = (int)xmin, r1 = (int)xmax, r2 = (int)ymin, r3 = (int)ymax;
    if(!valid){ r0=0; r1=0; r2=0; r3=0; }
    #pragma unroll
    for(int d=0;d<7;++d) out[t*7+d] = bf[d];
    out[N*7 + t] = sf;
    out[N*8 + t] = valid ? 1.f : 0.f;
    out[N*9 + t*4 + 0] = (float)r0;
    out[N*9 + t*4 + 1] = (float)r1;
    out[N*9 + t*4 + 2] = (float)r2;
    out[N*9 + t*4 + 3] = (float)r3;
}

extern "C" void kernel_launch(void* const* d_in, const int* in_sizes, int n_in,
                              void* d_out, int out_size, void* d_ws, size_t ws_size,
                              hipStream_t stream) {
    const float* boxes  = (const float*)d_in[0];
    const float* scores = (const float*)d_in[1];
    const int*   fhp    = (const int*)d_in[2];
    const int*   fwp    = (const int*)d_in[3];
    float* out = (float*)d_out;
    char* ws = (char*)d_ws;
    ull*      adj   = (ull*)(ws + ADJ_OFF);        // 32768 B
    int*      cnt   = (int*)(ws + CNT_OFF);        // 64 B
    unsigned* pairs = (unsigned*)(ws + PAIRS_OFF); // rest

    long long avail = (long long)ws_size - (long long)PAIRS_OFF;
    int cap = (int)(avail > 0 ? avail/4 : 0);
    if(cap > N*N) cap = N*N;

    init_kernel<<<1, 1, 0, stream>>>(cnt);
    pair_kernel<<<N, 512, 0, stream>>>(boxes, adj, cnt, pairs, cap);
    geom_kernel<<<64, 64, 0, stream>>>(boxes, pairs, cnt, adj, cap);
    cluster_fuse_kernel<<<1, 512, 0, stream>>>(boxes, scores, adj, fhp, fwp, out);
}